// Round 1
// baseline (2311.397 us; speedup 1.0000x reference)
//
#include <hip/hip_runtime.h>

typedef _Float16 h8 __attribute__((ext_vector_type(8)));
typedef _Float16 hv4 __attribute__((ext_vector_type(4)));
typedef float f4 __attribute__((ext_vector_type(4)));

#define SEQ_LEN 50
#define HID 64
#define HSTRIDE 76  // halves; 152B row pitch -> conflict-free b64 A-frag reads

__device__ __forceinline__ float fast_sigmoid(float v) {
    // 1/(1+e^-v); saturates cleanly: e^inf -> inf -> rcp -> 0
    return __builtin_amdgcn_rcpf(1.0f + __expf(-v));
}
__device__ __forceinline__ float fast_tanh(float v) {
    // (e^2v-1)/(e^2v+1) = 1 - 2/(1+e^2v); saturates to +/-1
    return 1.0f - 2.0f * __builtin_amdgcn_rcpf(1.0f + __expf(2.0f * v));
}

// Block = 128 threads = 2 waves, owns 16 sequences.
// Wave w computes n-tiles {g*4 + 2w + d : g in 0..3 (i,f,g,o), d in 0..1},
// i.e. gate values for units u = 32w .. 32w+31 of all 16 sequences.
// C-layout (16x16x32): col = lane&15 (n within tile), row = quad*4 + reg (seq).
// A-layout: A[m=lane&15][k=quad*8+j]; B: B[k=quad*8+j][n=lane&15] read from
// row-major W_hh[n][k] (the m97 gemm_bt precedent).
__global__ __launch_bounds__(128, 2)
void lstm_fused(const float* __restrict__ x,
                const float* __restrict__ W_ih,
                const float* __restrict__ W_hh,
                const float* __restrict__ b_ih,
                const float* __restrict__ b_hh,
                const float* __restrict__ W_fc,
                const float* __restrict__ b_fc,
                float* __restrict__ out)
{
    __shared__ _Float16 sH[2][16 * HSTRIDE];  // h double-buffer, fp16
    __shared__ float    sX[16 * SEQ_LEN];     // staged x tile, fp32

    const int tid  = threadIdx.x;
    const int wave = tid >> 6;
    const int lane = tid & 63;
    const int col  = lane & 15;
    const int quad = lane >> 4;
    const int seqBase = blockIdx.x << 4;

    // ---- stage x: 16 seqs x 50 floats = 800 floats, contiguous & 16B-aligned
    {
        const f4* gx = (const f4*)(x + (size_t)seqBase * SEQ_LEN);
        f4* sx = (f4*)sX;
        #pragma unroll
        for (int i = 0; i < 2; ++i) {
            int idx = tid + i * 128;
            if (idx < (16 * SEQ_LEN) / 4) sx[idx] = gx[idx];
        }
    }
    // ---- zero both h buffers (h0 = 0)
    for (int i = tid; i < 2 * 16 * HSTRIDE; i += 128)
        ((_Float16*)sH)[i] = (_Float16)0.0f;

    // ---- W_hh as resident fp16 B-fragments; per-tile xproj constants
    h8 Bf[8][2];
    float wih[8], bs[8];
    #pragma unroll
    for (int g = 0; g < 4; ++g) {
        #pragma unroll
        for (int d = 0; d < 2; ++d) {
            const int tt = g * 2 + d;
            const int n  = (g * 4 + 2 * wave + d) * 16 + col;
            wih[tt] = W_ih[n];
            bs[tt]  = b_ih[n] + b_hh[n];
            #pragma unroll
            for (int kf = 0; kf < 2; ++kf) {
                const float* wp = W_hh + n * HID + kf * 32 + quad * 8;
                f4 lo = *(const f4*)wp;
                f4 hi = *(const f4*)(wp + 4);
                h8 b;
                b[0] = (_Float16)lo[0]; b[1] = (_Float16)lo[1];
                b[2] = (_Float16)lo[2]; b[3] = (_Float16)lo[3];
                b[4] = (_Float16)hi[0]; b[5] = (_Float16)hi[1];
                b[6] = (_Float16)hi[2]; b[7] = (_Float16)hi[3];
                Bf[tt][kf] = b;
            }
        }
    }

    float c[2][4];
    #pragma unroll
    for (int d = 0; d < 2; ++d)
        #pragma unroll
        for (int r = 0; r < 4; ++r) c[d][r] = 0.0f;

    __syncthreads();

    #pragma unroll 2
    for (int t = 0; t < SEQ_LEN; ++t) {
        const _Float16* hb = sH[t & 1];
        _Float16*       hw = sH[(t + 1) & 1];

        // x_t for this lane's 4 rows (broadcast ds_read, conflict-free)
        float xq[4];
        #pragma unroll
        for (int r = 0; r < 4; ++r) xq[r] = sX[(quad * 4 + r) * SEQ_LEN + t];

        // A-fragments of current h (two b64 reads each; 152B pitch -> no conflicts)
        h8 A[2];
        #pragma unroll
        for (int kf = 0; kf < 2; ++kf) {
            const _Float16* p = hb + col * HSTRIDE + kf * 32 + quad * 8;
            hv4 a0 = *(const hv4*)p;
            hv4 a1 = *(const hv4*)(p + 4);
            A[kf] = __builtin_shufflevector(a0, a1, 0, 1, 2, 3, 4, 5, 6, 7);
        }

        // gates = x_t*W_ih + (b_ih+b_hh) + h @ W_hh^T   (fp32 accumulate)
        f4 acc[8];
        #pragma unroll
        for (int tt = 0; tt < 8; ++tt) {
            f4 a;
            #pragma unroll
            for (int r = 0; r < 4; ++r) a[r] = fmaf(xq[r], wih[tt], bs[tt]);
            a = __builtin_amdgcn_mfma_f32_16x16x32_f16(A[0], Bf[tt][0], a, 0, 0, 0);
            a = __builtin_amdgcn_mfma_f32_16x16x32_f16(A[1], Bf[tt][1], a, 0, 0, 0);
            acc[tt] = a;
        }

        // activations + state update; i/f/g/o for unit u live in the same lane/reg
        #pragma unroll
        for (int d = 0; d < 2; ++d) {
            #pragma unroll
            for (int r = 0; r < 4; ++r) {
                float ig = fast_sigmoid(acc[0 * 2 + d][r]);
                float fg = fast_sigmoid(acc[1 * 2 + d][r]);
                float gg = fast_tanh  (acc[2 * 2 + d][r]);
                float og = fast_sigmoid(acc[3 * 2 + d][r]);
                float cc = fmaf(fg, c[d][r], ig * gg);
                c[d][r] = cc;
                float hh = og * fast_tanh(cc);
                hw[(quad * 4 + r) * HSTRIDE + 32 * wave + d * 16 + col] = (_Float16)hh;
            }
        }
        __syncthreads();
    }

    // ---- epilogue: final h is in sH[0] (t=49 wrote buffer (49+1)&1 = 0)
    if (lane < 24) {
        const int sl = wave * 8 + lane / 3;  // sequence within tile
        const int nc = lane % 3;             // class
        const _Float16* hp = sH[0] + sl * HSTRIDE;
        float a = b_fc[nc];
        #pragma unroll
        for (int u = 0; u < HID; ++u)
            a = fmaf((float)hp[u], W_fc[nc * HID + u], a);
        out[(size_t)(seqBase + sl) * 3 + nc] = a;
    }
}

extern "C" void kernel_launch(void* const* d_in, const int* in_sizes, int n_in,
                              void* d_out, int out_size, void* d_ws, size_t ws_size,
                              hipStream_t stream) {
    const float* x    = (const float*)d_in[0];
    const float* W_ih = (const float*)d_in[1];
    const float* W_hh = (const float*)d_in[2];
    const float* b_ih = (const float*)d_in[3];
    const float* b_hh = (const float*)d_in[4];
    const float* W_fc = (const float*)d_in[5];
    const float* b_fc = (const float*)d_in[6];
    float* out = (float*)d_out;

    const int nSeq   = in_sizes[0] / SEQ_LEN;  // 512000
    const int blocks = nSeq / 16;              // 32000

    hipLaunchKernelGGL(lstm_fused, dim3(blocks), dim3(128), 0, stream,
                       x, W_ih, W_hh, b_ih, b_hh, W_fc, b_fc, out);
}